// Round 1
// baseline (163.992 us; speedup 1.0000x reference)
//
#include <hip/hip_runtime.h>

#define BLK 256   // threads per block; each thread owns one i in kernel 1/2
#define JS  8     // j-dimension splits (grid.y) -> 64*8 = 512 blocks, 2/CU

// Kernel 1: partial risk-set sums.
// part[q*n + i] = sum over j in q-th chunk of (time[j] >= time[i]) * exp(risk[j])
__global__ void cox_partial_sums(const float* __restrict__ risk,
                                 const float* __restrict__ tm,
                                 float* __restrict__ part, int n) {
    __shared__ float st[BLK];
    __shared__ float se[BLK];
    const int tid = threadIdx.x;
    const int i   = blockIdx.x * BLK + tid;
    const int jch = n / JS;                 // j-chunk length (2048)
    const int j0  = blockIdx.y * jch;
    const float ti = tm[i];
    float sum = 0.f;
    for (int jb = 0; jb < jch; jb += BLK) {
        const int j = j0 + jb + tid;
        st[tid] = tm[j];
        se[tid] = __expf(risk[j]);
        __syncthreads();
        #pragma unroll 16
        for (int k = 0; k < BLK; ++k)
            sum += (st[k] >= ti) ? se[k] : 0.f;   // LDS broadcast reads: conflict-free
        __syncthreads();
    }
    part[blockIdx.y * n + i] = sum;
}

// Kernel 2: combine partials, per-i contribution, block-reduce num/den.
__global__ void cox_contrib(const float* __restrict__ risk,
                            const float* __restrict__ event,
                            const float* __restrict__ part,
                            float* __restrict__ bnum,
                            float* __restrict__ bden, int n) {
    const int tid = threadIdx.x;
    const int i   = blockIdx.x * BLK + tid;
    float s = 0.f;
    #pragma unroll
    for (int q = 0; q < JS; ++q) s += part[q * n + i];
    const float ev = event[i];
    float num = (risk[i] - logf(s)) * ev;
    float den = ev;
    // wave-64 reduce
    #pragma unroll
    for (int off = 32; off > 0; off >>= 1) {
        num += __shfl_down(num, off);
        den += __shfl_down(den, off);
    }
    __shared__ float snum[BLK / 64];
    __shared__ float sden[BLK / 64];
    const int wave = tid >> 6;
    if ((tid & 63) == 0) { snum[wave] = num; sden[wave] = den; }
    __syncthreads();
    if (tid == 0) {
        float tn = 0.f, td = 0.f;
        #pragma unroll
        for (int w = 0; w < BLK / 64; ++w) { tn += snum[w]; td += sden[w]; }
        bnum[blockIdx.x] = tn;
        bden[blockIdx.x] = td;
    }
}

// Kernel 3: final reduce over nb (=64) block partials -> scalar loss.
__global__ void cox_final(const float* __restrict__ bnum,
                          const float* __restrict__ bden,
                          float* __restrict__ out, int nb) {
    const int tid = threadIdx.x;
    float num = (tid < nb) ? bnum[tid] : 0.f;
    float den = (tid < nb) ? bden[tid] : 0.f;
    #pragma unroll
    for (int off = 32; off > 0; off >>= 1) {
        num += __shfl_down(num, off);
        den += __shfl_down(den, off);
    }
    if (tid == 0) out[0] = -num / den;
}

extern "C" void kernel_launch(void* const* d_in, const int* in_sizes, int n_in,
                              void* d_out, int out_size, void* d_ws, size_t ws_size,
                              hipStream_t stream) {
    const float* risk  = (const float*)d_in[0];
    const float* tm    = (const float*)d_in[1];
    const float* event = (const float*)d_in[2];
    float* out = (float*)d_out;
    const int n  = in_sizes[0];          // 16384
    const int nb = n / BLK;              // 64 i-blocks

    // ws layout: part[JS*n] | bnum[nb] | bden[nb]   (~512 KB + 512 B)
    float* part = (float*)d_ws;
    float* bnum = part + (size_t)JS * n;
    float* bden = bnum + nb;

    dim3 g1(nb, JS);
    cox_partial_sums<<<g1, BLK, 0, stream>>>(risk, tm, part, n);
    cox_contrib<<<nb, BLK, 0, stream>>>(risk, event, part, bnum, bden, n);
    cox_final<<<1, 64, 0, stream>>>(bnum, bden, out, nb);
}

// Round 2
// 97.235 us; speedup vs baseline: 1.6866x; 1.6866x over previous
//
#include <hip/hip_runtime.h>

#define BLK  256   // threads per block
#define IT   8     // i-values per thread in kernel 1 (register blocking)
#define TILE 256   // j-tile staged in LDS (== BLK)

// Kernel 1: partial risk-set sums, register-blocked 8x over i.
// part[q*n + i] = sum_{j in chunk q} (time[j] >= time[i]) * exp(risk[j])
// Also zero-inits the accumulator (stream-ordered before kernel 2).
__global__ void cox_partial(const float* __restrict__ risk,
                            const float* __restrict__ tm,
                            float* __restrict__ part,
                            float* __restrict__ acc,   // [0]=num,[1]=den,[2]=counter(u32)
                            int n, int jch) {
    __shared__ float st[TILE];
    __shared__ float se[TILE];
    const int tid = threadIdx.x;
    const int i0  = blockIdx.x * (BLK * IT);
    const int j0  = blockIdx.y * jch;

    if (blockIdx.x == 0 && blockIdx.y == 0 && tid == 0) {
        acc[0] = 0.f; acc[1] = 0.f;
        ((unsigned*)acc)[2] = 0u;
    }

    float ti[IT], sum[IT];
    #pragma unroll
    for (int r = 0; r < IT; ++r) {
        ti[r]  = tm[i0 + r * BLK + tid];   // coalesced
        sum[r] = 0.f;
    }

    for (int jb = 0; jb < jch; jb += TILE) {
        const int j = j0 + jb + tid;
        st[tid] = tm[j];
        se[tid] = __expf(risk[j]);
        __syncthreads();
        const float4* st4 = (const float4*)st;
        const float4* se4 = (const float4*)se;
        #pragma unroll 4
        for (int k4 = 0; k4 < TILE / 4; ++k4) {
            const float4 t4 = st4[k4];   // ds_read_b128, broadcast: conflict-free
            const float4 e4 = se4[k4];
            #pragma unroll
            for (int r = 0; r < IT; ++r) {
                sum[r] += (t4.x >= ti[r]) ? e4.x : 0.f;
                sum[r] += (t4.y >= ti[r]) ? e4.y : 0.f;
                sum[r] += (t4.z >= ti[r]) ? e4.z : 0.f;
                sum[r] += (t4.w >= ti[r]) ? e4.w : 0.f;
            }
        }
        __syncthreads();
    }

    float* p = part + (size_t)blockIdx.y * n + i0;
    #pragma unroll
    for (int r = 0; r < IT; ++r)
        p[r * BLK + tid] = sum[r];       // coalesced, deterministic (no atomics)
}

// Kernel 2: combine j-partials, per-i contribution, block reduce, atomic
// last-block finalize (replaces old kernel 3).
__global__ void cox_finish(const float* __restrict__ risk,
                           const float* __restrict__ event,
                           const float* __restrict__ part,
                           float* __restrict__ acc,
                           float* __restrict__ out,
                           int n, int js, int nblocks) {
    const int tid = threadIdx.x;
    const int i   = blockIdx.x * BLK + tid;
    float s = 0.f;
    for (int q = 0; q < js; ++q) s += part[(size_t)q * n + i];  // coalesced per q
    const float ev = event[i];
    float num = (risk[i] - logf(s)) * ev;
    float den = ev;
    #pragma unroll
    for (int off = 32; off > 0; off >>= 1) {
        num += __shfl_down(num, off);
        den += __shfl_down(den, off);
    }
    __shared__ float sn[BLK / 64], sd[BLK / 64];
    const int wave = tid >> 6;
    if ((tid & 63) == 0) { sn[wave] = num; sd[wave] = den; }
    __syncthreads();
    if (tid == 0) {
        float tn = 0.f, td = 0.f;
        #pragma unroll
        for (int w = 0; w < BLK / 64; ++w) { tn += sn[w]; td += sd[w]; }
        atomicAdd(&acc[0], tn);
        atomicAdd(&acc[1], td);
        __threadfence();
        const unsigned old = atomicAdd(&((unsigned*)acc)[2], 1u);
        if (old == (unsigned)(nblocks - 1)) {
            const float fn = atomicAdd(&acc[0], 0.f);  // L2-coherent read-back
            const float fd = atomicAdd(&acc[1], 0.f);
            out[0] = -fn / fd;
        }
    }
}

extern "C" void kernel_launch(void* const* d_in, const int* in_sizes, int n_in,
                              void* d_out, int out_size, void* d_ws, size_t ws_size,
                              hipStream_t stream) {
    const float* risk  = (const float*)d_in[0];
    const float* tm    = (const float*)d_in[1];
    const float* event = (const float*)d_in[2];
    float* out = (float*)d_out;
    const int n = in_sizes[0];           // 16384

    // j-splits: as many as ws can hold (JS=64 -> 4 MB partials; JS=8 known OK).
    int js = 64;
    while (js > 8 && ((size_t)js * n + 8) * sizeof(float) > ws_size) js >>= 1;
    const int jch = n / js;              // multiple of TILE for js<=64, n=16384

    float* part = (float*)d_ws;
    float* acc  = part + (size_t)js * n; // [num, den, counter]

    const int nib = n / (BLK * IT);      // 8 i-blocks
    const int nb2 = n / BLK;             // 64 blocks in kernel 2

    dim3 g1(nib, js);
    cox_partial<<<g1, BLK, 0, stream>>>(risk, tm, part, acc, n, jch);
    cox_finish<<<nb2, BLK, 0, stream>>>(risk, event, part, acc, out, n, js, nb2);
}